// Round 6
// baseline (419.368 us; speedup 1.0000x reference)
//
#include <hip/hip_runtime.h>
#include <hip/hip_bf16.h>

#define B_ 128
#define N_ 320
#define C_ 256
#define H_ 8
#define HQKV 1536
#define DH 1024
#define MROWS 40960
#define EPS 1e-5f
#define SCALE 0.17677669529663687f

typedef __attribute__((ext_vector_type(4))) float f32x4;
typedef __attribute__((ext_vector_type(8))) short short8_t;
typedef __attribute__((ext_vector_type(4))) short short4_t;

__device__ inline float bf2f(unsigned short u) { return __uint_as_float(((unsigned)u) << 16); }
__device__ inline unsigned short f2bf(float f) {
    unsigned u = __float_as_uint(f);
    u += 0x7FFF + ((u >> 16) & 1);
    return (unsigned short)(u >> 16);
}

// A&S 7.1.26 erf (|err|<1.5e-7) -> exact-GELU substitute, ~14 VALU ops
__device__ inline float gelu_f(float v) {
    float x = v * 0.70710678118f;
    float ax = fabsf(x);
    float t = 1.0f / (1.0f + 0.3275911f * ax);
    float y = t * (0.254829592f + t * (-0.284496736f + t * (1.421413741f +
              t * (-1.453152027f + t * 1.061405429f))));
    float er = 1.0f - y * __expf(-x * x);
    er = copysignf(er, x);
    return 0.5f * v * (1.0f + er);
}

#define GLD16(gp, lp)                                                                  \
    __builtin_amdgcn_global_load_lds((const __attribute__((address_space(1))) void*)(gp), \
                                     (__attribute__((address_space(3))) void*)(lp), 16, 0, 0)

__global__ void conv_bf16(const float* __restrict__ in, unsigned short* __restrict__ out, int n4) {
    int i = blockIdx.x * 256 + threadIdx.x;
    if (i < n4) {
        f32x4 v = ((const f32x4*)in)[i];
        short4_t o;
#pragma unroll
        for (int j = 0; j < 4; ++j) o[j] = (short)f2bf(v[j]);
        ((short4_t*)out)[i] = o;
    }
}

// ---- GEMM1: qkv = x @ Wqkv^T via global_load_lds (m97 structure); routes q/k/v; fused BN stats ----
__global__ __launch_bounds__(256) void gemm_qkv(const unsigned short* __restrict__ A,
                                                const unsigned short* __restrict__ Bm,
                                                unsigned short* __restrict__ qkB,
                                                unsigned short* __restrict__ vT,
                                                float* __restrict__ sum1, float* __restrict__ sumsq1) {
    __shared__ unsigned short lA[128 * 32];
    __shared__ unsigned short lB[128 * 32];
    const int tid = threadIdx.x;
    const int lane = tid & 63, wid = tid >> 6;
    const int wm = wid >> 1, wn = wid & 1;
    const int lr = lane & 15, g = lane >> 4, lk = g * 8;
    const int m0 = blockIdx.y * 128, n0 = blockIdx.x * 128;
    const int wb0 = tid & 192;  // wave base within 256
    f32x4 acc[4][4] = {};
    for (int k0 = 0; k0 < 256; k0 += 32) {
        __syncthreads();
#pragma unroll
        for (int j = 0; j < 2; ++j) {
            int idx = j * 256 + tid;
            int wb = j * 256 + wb0;
            GLD16(&A[(size_t)(m0 + (idx >> 2)) * 256 + k0 + (idx & 3) * 8], &lA[(size_t)wb * 8]);
            GLD16(&Bm[(size_t)(n0 + (idx >> 2)) * 256 + k0 + (idx & 3) * 8], &lB[(size_t)wb * 8]);
        }
        __syncthreads();
        short8_t af[4], bfr[4];
#pragma unroll
        for (int i = 0; i < 4; ++i) af[i] = *(short8_t*)&lA[(wm * 64 + i * 16 + lr) * 32 + lk];
#pragma unroll
        for (int j = 0; j < 4; ++j) bfr[j] = *(short8_t*)&lB[(wn * 64 + j * 16 + lr) * 32 + lk];
#pragma unroll
        for (int i = 0; i < 4; ++i)
#pragma unroll
            for (int j = 0; j < 4; ++j)
                acc[i][j] = __builtin_amdgcn_mfma_f32_16x16x32_bf16(af[i], bfr[j], acc[i][j], 0, 0, 0);
    }
    float cs[4] = {0.f, 0.f, 0.f, 0.f}, css[4] = {0.f, 0.f, 0.f, 0.f};
#pragma unroll
    for (int i = 0; i < 4; ++i) {
#pragma unroll
        for (int r = 0; r < 4; ++r) {
            int row = m0 + wm * 64 + i * 16 + g * 4 + r;
            int bq = row / 320;
            int n = row - bq * 320;
#pragma unroll
            for (int j = 0; j < 4; ++j) {
                float val = acc[i][j][r];
                cs[j] += val;
                css[j] += val * val;
                int col = n0 + wn * 64 + j * 16 + lr;
                int hh = col / 192;
                int cm = col - hh * 192;
                if (cm < 64)
                    qkB[((size_t)(bq * 8 + hh) * 320 + n) * 64 + cm] = f2bf(val);
                else
                    vT[((size_t)(bq * 8 + hh) * 128 + (cm - 64)) * 320 + n] = f2bf(val);
            }
        }
    }
    __syncthreads();
    float* red_s = (float*)lA;
    float* red_ss = (float*)lB;
#pragma unroll
    for (int j = 0; j < 4; ++j) {
        int c = wn * 64 + j * 16 + lr;
        red_s[(wm * 4 + g) * 128 + c] = cs[j];
        red_ss[(wm * 4 + g) * 128 + c] = css[j];
    }
    __syncthreads();
    if (tid < 128) {
        float s = 0.f;
#pragma unroll
        for (int u = 0; u < 8; ++u) s += red_s[u * 128 + tid];
        atomicAdd(&sum1[n0 + tid], s);
    } else {
        int c = tid - 128;
        float s = 0.f;
#pragma unroll
        for (int u = 0; u < 8; ++u) s += red_ss[u * 128 + c];
        atomicAdd(&sumsq1[n0 + c], s);
    }
}

// ---- GEMM2: d_out = attnout @ Wproj^T (f32) via global_load_lds + fused stats ----
__global__ __launch_bounds__(256) void gemm_proj(const unsigned short* __restrict__ A,
                                                 const unsigned short* __restrict__ Bm,
                                                 float* __restrict__ Cout,
                                                 float* __restrict__ sum2, float* __restrict__ sumsq2) {
    __shared__ unsigned short lA[128 * 32];
    __shared__ unsigned short lB[128 * 32];
    const int tid = threadIdx.x;
    const int lane = tid & 63, wid = tid >> 6;
    const int wm = wid >> 1, wn = wid & 1;
    const int lr = lane & 15, g = lane >> 4, lk = g * 8;
    const int m0 = blockIdx.y * 128, n0 = blockIdx.x * 128;
    const int wb0 = tid & 192;
    f32x4 acc[4][4] = {};
    for (int k0 = 0; k0 < 1024; k0 += 32) {
        __syncthreads();
#pragma unroll
        for (int j = 0; j < 2; ++j) {
            int idx = j * 256 + tid;
            int wb = j * 256 + wb0;
            GLD16(&A[(size_t)(m0 + (idx >> 2)) * 1024 + k0 + (idx & 3) * 8], &lA[(size_t)wb * 8]);
            GLD16(&Bm[(size_t)(n0 + (idx >> 2)) * 1024 + k0 + (idx & 3) * 8], &lB[(size_t)wb * 8]);
        }
        __syncthreads();
        short8_t af[4], bfr[4];
#pragma unroll
        for (int i = 0; i < 4; ++i) af[i] = *(short8_t*)&lA[(wm * 64 + i * 16 + lr) * 32 + lk];
#pragma unroll
        for (int j = 0; j < 4; ++j) bfr[j] = *(short8_t*)&lB[(wn * 64 + j * 16 + lr) * 32 + lk];
#pragma unroll
        for (int i = 0; i < 4; ++i)
#pragma unroll
            for (int j = 0; j < 4; ++j)
                acc[i][j] = __builtin_amdgcn_mfma_f32_16x16x32_bf16(af[i], bfr[j], acc[i][j], 0, 0, 0);
    }
    float cs[4] = {0.f, 0.f, 0.f, 0.f}, css[4] = {0.f, 0.f, 0.f, 0.f};
#pragma unroll
    for (int i = 0; i < 4; ++i) {
#pragma unroll
        for (int r = 0; r < 4; ++r) {
            int row = m0 + wm * 64 + i * 16 + g * 4 + r;
#pragma unroll
            for (int j = 0; j < 4; ++j) {
                float val = acc[i][j][r];
                cs[j] += val;
                css[j] += val * val;
                int col = n0 + wn * 64 + j * 16 + lr;
                Cout[(size_t)row * 256 + col] = val;
            }
        }
    }
    __syncthreads();
    float* red_s = (float*)lA;
    float* red_ss = (float*)lB;
#pragma unroll
    for (int j = 0; j < 4; ++j) {
        int c = wn * 64 + j * 16 + lr;
        red_s[(wm * 4 + g) * 128 + c] = cs[j];
        red_ss[(wm * 4 + g) * 128 + c] = css[j];
    }
    __syncthreads();
    if (tid < 128) {
        float s = 0.f;
#pragma unroll
        for (int u = 0; u < 8; ++u) s += red_s[u * 128 + tid];
        atomicAdd(&sum2[n0 + tid], s);
    } else {
        int c = tid - 128;
        float s = 0.f;
#pragma unroll
        for (int u = 0; u < 8; ++u) s += red_ss[u * 128 + c];
        atomicAdd(&sumsq2[n0 + c], s);
    }
}

__global__ void bn_finalize(const float* __restrict__ sum, const float* __restrict__ sumsq,
                            const float* __restrict__ g, const float* __restrict__ b,
                            float* __restrict__ scale, float* __restrict__ shift, int C, float invM) {
    int c = blockIdx.x * 256 + threadIdx.x;
    if (c < C) {
        float mean = sum[c] * invM;
        float var = sumsq[c] * invM - mean * mean;
        float sc = g[c] * rsqrtf(var + EPS);
        scale[c] = sc;
        shift[c] = b[c] - mean * sc;
    }
}

__global__ void prep_w(const float* __restrict__ scale1, const float* __restrict__ shift1,
                       float* __restrict__ wq, float* __restrict__ w2) {
    int c = threadIdx.x;
    if (c < 256) {
        int h = c >> 5, cc = c & 31;
        int qch = h * 192 + cc, kch = qch + 32;
        wq[c] = scale1[qch] * scale1[kch] * SCALE;
        w2[c] = shift1[qch] * scale1[kch] * SCALE;
    }
}

__global__ void uk_kernel(const unsigned short* __restrict__ qkB, const float* __restrict__ w2,
                          float* __restrict__ uk) {
    int idx = blockIdx.x * 256 + threadIdx.x;
    if (idx < 128 * 8 * 320) {
        int bh = idx / 320;
        int h = bh & 7;
        const unsigned short* kp = &qkB[(size_t)idx * 64 + 32];
        float s = 0.f;
#pragma unroll
        for (int c4 = 0; c4 < 4; ++c4) {
            short8_t kk = *(const short8_t*)&kp[c4 * 8];
#pragma unroll
            for (int j = 0; j < 8; ++j) s += bf2f((unsigned short)kk[j]) * w2[(h << 5) + c4 * 8 + j];
        }
        uk[idx] = s;
    }
}

__global__ void bias_build(const float* __restrict__ ab, const int* __restrict__ idxs,
                           unsigned short* __restrict__ biasb, int n_off) {
    int i = blockIdx.x * 256 + threadIdx.x;
    if (i < H_ * N_ * N_) {
        int h = i / (N_ * N_);
        int r = i % (N_ * N_);
        biasb[i] = f2bf(ab[h * n_off + idxs[r]]);
    }
}

// ---- attention v4: block=(h,b), qt loop inside; K staged once in padded LDS (reused 20x);
// phase-split QK/softmax/PV with 4-wave P sharing ----
__global__ __launch_bounds__(256) void attn_kernel(const unsigned short* __restrict__ qkB,
                                                   const unsigned short* __restrict__ vT,
                                                   const float* __restrict__ wq,
                                                   const float* __restrict__ uk,
                                                   const unsigned short* __restrict__ biasb,
                                                   const float* __restrict__ scale1,
                                                   const float* __restrict__ shift1,
                                                   unsigned short* __restrict__ attnout) {
    extern __shared__ char smem[];
    unsigned short* Klds = (unsigned short*)smem;  // [320][40] padded, conflict-free
    unsigned short* Plds = Klds + 320 * 40;        // [4][10][16][40]
    float* sums = (float*)(Plds + 4 * 10 * 16 * 40);  // [64]
    const int tid = threadIdx.x;
    const int lane = tid & 63, wid = tid >> 6;
    const int lr = lane & 15, g = lane >> 4;
    const int h = blockIdx.x, b = blockIdx.y;
    const int bh = b * 8 + h;

    // stage K once (raw bf16 copy, padded rows)
    for (int idx = tid; idx < 320 * 4; idx += 256) {
        int m = idx >> 2, cg = idx & 3;
        *(short8_t*)&Klds[m * 40 + cg * 8] =
            *(const short8_t*)&qkB[((size_t)bh * 320 + m) * 64 + 32 + cg * 8];
    }
    __syncthreads();

    const unsigned short* biasrow = &biasb[(size_t)h * 320 * 320];
    const float* ukrow = &uk[(size_t)bh * 320];
    const unsigned short* Vb = &vT[(size_t)bh * 128 * 320 + g * 8];
    float svv[2], tvv[2];
#pragma unroll
    for (int dtl = 0; dtl < 2; ++dtl) {
        int ch = h * 192 + 64 + wid * 32 + dtl * 16 + lr;
        svv[dtl] = scale1[ch];
        tvv[dtl] = shift1[ch];
    }

    for (int qt = 0; qt < 5; ++qt) {
        // Q fragment (wq folded)
        int qrow = qt * 64 + wid * 16 + lr;
        short8_t qraw = *(const short8_t*)&qkB[((size_t)bh * 320 + qrow) * 64 + g * 8];
        short8_t aq;
#pragma unroll
        for (int j = 0; j < 8; ++j)
            aq[j] = (short)f2bf(bf2f((unsigned short)qraw[j]) * wq[(h << 5) + g * 8 + j]);

        // phase 1: QK^T from LDS
        f32x4 sacc[20];
#pragma unroll
        for (int t = 0; t < 20; ++t) {
            short8_t bk = *(short8_t*)&Klds[(t * 16 + lr) * 40 + g * 8];
            f32x4 z = {};
            sacc[t] = __builtin_amdgcn_mfma_f32_16x16x32_bf16(aq, bk, z, 0, 0, 0);
        }

        // phase 2: bias + exp -> P slab (own wave), rowsum
        const int nloc0 = qt * 64 + wid * 16 + g * 4;
        float sumr[4] = {0.f, 0.f, 0.f, 0.f};
#pragma unroll
        for (int t = 0; t < 20; ++t) {
            float ukv = ukrow[t * 16 + lr];
#pragma unroll
            for (int r = 0; r < 4; ++r) {
                float s = sacc[t][r] + ukv + bf2f(biasrow[(size_t)(nloc0 + r) * 320 + t * 16 + lr]);
                float p = __expf(s);
                sumr[r] += p;
                Plds[((wid * 10 + (t >> 1)) * 16 + g * 4 + r) * 40 + (t & 1) * 16 + lr] = f2bf(p);
            }
        }
#pragma unroll
        for (int r = 0; r < 4; ++r) {
#pragma unroll
            for (int ms = 1; ms < 16; ms <<= 1) sumr[r] += __shfl_xor(sumr[r], ms);
            if (lr == 0) sums[wid * 16 + g * 4 + r] = sumr[r];
        }
        __syncthreads();

        // phase 3: PV. wave owns O-cols [wid*32, wid*32+32); V read once per block per qt
        f32x4 oacc[4][2] = {};
#pragma unroll
        for (int t = 0; t < 10; ++t) {
            short8_t bv0 = *(const short8_t*)&Vb[(size_t)(wid * 32 + lr) * 320 + t * 32];
            short8_t bv1 = *(const short8_t*)&Vb[(size_t)(wid * 32 + 16 + lr) * 320 + t * 32];
#pragma unroll
            for (int qw = 0; qw < 4; ++qw) {
                short8_t ap = *(short8_t*)&Plds[((qw * 10 + t) * 16 + lr) * 40 + g * 8];
                oacc[qw][0] = __builtin_amdgcn_mfma_f32_16x16x32_bf16(ap, bv0, oacc[qw][0], 0, 0, 0);
                oacc[qw][1] = __builtin_amdgcn_mfma_f32_16x16x32_bf16(ap, bv1, oacc[qw][1], 0, 0, 0);
            }
        }

        // epilogue: normalize, fold V-BN, GELU
#pragma unroll
        for (int qw = 0; qw < 4; ++qw) {
#pragma unroll
            for (int r = 0; r < 4; ++r) {
                float inv = 1.0f / sums[qw * 16 + g * 4 + r];
                size_t nrow = (size_t)b * 320 + qt * 64 + qw * 16 + g * 4 + r;
#pragma unroll
                for (int dtl = 0; dtl < 2; ++dtl) {
                    float v = oacc[qw][dtl][r] * inv * svv[dtl] + tvv[dtl];
                    attnout[nrow * 1024 + h * 128 + wid * 32 + dtl * 16 + lr] = f2bf(gelu_f(v));
                }
            }
        }
        __syncthreads();  // protect P slab + sums before next qt
    }
}

__global__ void bn_apply(float* __restrict__ out, const float* __restrict__ scale,
                         const float* __restrict__ shift) {
    int i = blockIdx.x * 256 + threadIdx.x;
    const int total = MROWS * C_ / 4;
    for (; i < total; i += gridDim.x * 256) {
        f32x4 v = *(const f32x4*)&out[(size_t)i * 4];
        int c = (i * 4) & 255;
        f32x4 o;
#pragma unroll
        for (int j = 0; j < 4; ++j) o[j] = v[j] * scale[c + j] + shift[c + j];
        *(f32x4*)&out[(size_t)i * 4] = o;
    }
}

extern "C" void kernel_launch(void* const* d_in, const int* in_sizes, int n_in,
                              void* d_out, int out_size, void* d_ws, size_t ws_size,
                              hipStream_t stream) {
    const float* x = (const float*)d_in[0];
    const float* Wqkv = (const float*)d_in[1];
    const float* g1 = (const float*)d_in[2];
    const float* b1 = (const float*)d_in[3];
    const float* ab = (const float*)d_in[4];
    const float* Wproj = (const float*)d_in[5];
    const float* g2 = (const float*)d_in[6];
    const float* b2 = (const float*)d_in[7];
    const int* idxs = (const int*)d_in[8];
    const int n_off = in_sizes[4] / H_;

    char* ws = (char*)d_ws;
    unsigned short* qkB = (unsigned short*)ws;                       // 41.9MB
    unsigned short* vT = (unsigned short*)(ws + 41943040);           // 83.9MB
    unsigned short* attnout = (unsigned short*)(ws + 125829120);     // 83.9MB
    unsigned short* xb = attnout;                                    // overlap: dead before attn
    unsigned short* biasb = (unsigned short*)(ws + 209715200);       // 1.64MB bf16
    float* uk = (float*)(ws + 212992000);                            // 1.31MB
    unsigned short* wqb = (unsigned short*)(ws + 214302720);
    unsigned short* wpb = (unsigned short*)(ws + 215089152);
    float* stats = (float*)(ws + 215613440);
    float* sum1 = stats;
    float* sumsq1 = stats + 1536;
    float* sum2 = stats + 3072;
    float* sumsq2 = sum2 + 256;
    float* scale1 = sumsq2 + 256;
    float* shift1 = scale1 + 1536;
    float* scale2 = shift1 + 1536;
    float* shift2 = scale2 + 256;
    float* wq = shift2 + 256;
    float* w2 = wq + 256;

    hipMemsetAsync(stats, 0, 3584 * 4, stream);
    conv_bf16<<<dim3(10240), 256, 0, stream>>>(x, xb, 2621440);
    conv_bf16<<<dim3(384), 256, 0, stream>>>(Wqkv, wqb, 98304);
    conv_bf16<<<dim3(256), 256, 0, stream>>>(Wproj, wpb, 65536);
    bias_build<<<dim3(3200), 256, 0, stream>>>(ab, idxs, biasb, n_off);
    gemm_qkv<<<dim3(12, 320), 256, 0, stream>>>(xb, wqb, qkB, vT, sum1, sumsq1);
    bn_finalize<<<dim3(6), 256, 0, stream>>>(sum1, sumsq1, g1, b1, scale1, shift1, 1536, 1.0f / MROWS);
    prep_w<<<dim3(1), 256, 0, stream>>>(scale1, shift1, wq, w2);
    uk_kernel<<<dim3(1280), 256, 0, stream>>>(qkB, w2, uk);
    hipFuncSetAttribute((const void*)attn_kernel, hipFuncAttributeMaxDynamicSharedMemorySize, 77056);
    attn_kernel<<<dim3(8, 128), 256, 77056, stream>>>(qkB, vT, wq, uk, biasb, scale1, shift1, attnout);
    gemm_proj<<<dim3(2, 320), 256, 0, stream>>>(attnout, wpb, (float*)d_out, sum2, sumsq2);
    bn_finalize<<<dim3(1), 256, 0, stream>>>(sum2, sumsq2, g2, b2, scale2, shift2, 256, 1.0f / MROWS);
    bn_apply<<<dim3(2048), 256, 0, stream>>>((float*)d_out, scale2, shift2);
}

// Round 7
// 402.128 us; speedup vs baseline: 1.0429x; 1.0429x over previous
//
#include <hip/hip_runtime.h>
#include <hip/hip_bf16.h>

#define B_ 128
#define N_ 320
#define C_ 256
#define H_ 8
#define HQKV 1536
#define DH 1024
#define MROWS 40960
#define EPS 1e-5f
#define SCALE 0.17677669529663687f

typedef __attribute__((ext_vector_type(4))) float f32x4;
typedef __attribute__((ext_vector_type(8))) short short8_t;
typedef __attribute__((ext_vector_type(4))) short short4_t;

__device__ inline float bf2f(unsigned short u) { return __uint_as_float(((unsigned)u) << 16); }
__device__ inline unsigned short f2bf(float f) {
    unsigned u = __float_as_uint(f);
    u += 0x7FFF + ((u >> 16) & 1);
    return (unsigned short)(u >> 16);
}
__device__ inline unsigned int f2bf2(float a, float b) {
    __hip_bfloat162 h2 = __float22bfloat162_rn(make_float2(a, b));  // v_cvt_pk_bf16_f32
    return *(unsigned int*)&h2;
}

// A&S 7.1.26 erf (|err|<1.5e-7) -> exact-GELU substitute
__device__ inline float gelu_f(float v) {
    float x = v * 0.70710678118f;
    float ax = fabsf(x);
    float t = 1.0f / (1.0f + 0.3275911f * ax);
    float y = t * (0.254829592f + t * (-0.284496736f + t * (1.421413741f +
              t * (-1.453152027f + t * 1.061405429f))));
    float er = 1.0f - y * __expf(-x * x);
    er = copysignf(er, x);
    return 0.5f * v * (1.0f + er);
}

#define GLD16(gp, lp)                                                                  \
    __builtin_amdgcn_global_load_lds((const __attribute__((address_space(1))) void*)(gp), \
                                     (__attribute__((address_space(3))) void*)(lp), 16, 0, 0)

// one kernel converts x, Wqkv, Wproj to bf16
__global__ void conv_all(const float* __restrict__ x, const float* __restrict__ wqkv,
                         const float* __restrict__ wproj, unsigned short* __restrict__ xb,
                         unsigned short* __restrict__ wqb, unsigned short* __restrict__ wpb) {
    int i = blockIdx.x * 256 + threadIdx.x;
    const float* src;
    unsigned short* dst;
    int off;
    if (i < 2621440) { src = x; dst = xb; off = i; }
    else if (i < 2719744) { src = wqkv; dst = wqb; off = i - 2621440; }
    else if (i < 2785280) { src = wproj; dst = wpb; off = i - 2719744; }
    else return;
    f32x4 v = ((const f32x4*)src)[off];
    short4_t o;
#pragma unroll
    for (int j = 0; j < 4; ++j) o[j] = (short)f2bf(v[j]);
    ((short4_t*)dst)[off] = o;
}

// ---- GEMM1: qkv = x @ Wqkv^T via global_load_lds; routes q/k/v; fused BN stats ----
__global__ __launch_bounds__(256) void gemm_qkv(const unsigned short* __restrict__ A,
                                                const unsigned short* __restrict__ Bm,
                                                unsigned short* __restrict__ qkB,
                                                unsigned short* __restrict__ vT,
                                                float* __restrict__ sum1, float* __restrict__ sumsq1) {
    __shared__ unsigned short lA[128 * 32];
    __shared__ unsigned short lB[128 * 32];
    const int tid = threadIdx.x;
    const int lane = tid & 63, wid = tid >> 6;
    const int wm = wid >> 1, wn = wid & 1;
    const int lr = lane & 15, g = lane >> 4, lk = g * 8;
    const int m0 = blockIdx.y * 128, n0 = blockIdx.x * 128;
    const int wb0 = tid & 192;
    f32x4 acc[4][4] = {};
    for (int k0 = 0; k0 < 256; k0 += 32) {
        __syncthreads();
#pragma unroll
        for (int j = 0; j < 2; ++j) {
            int idx = j * 256 + tid;
            int wb = j * 256 + wb0;
            GLD16(&A[(size_t)(m0 + (idx >> 2)) * 256 + k0 + (idx & 3) * 8], &lA[(size_t)wb * 8]);
            GLD16(&Bm[(size_t)(n0 + (idx >> 2)) * 256 + k0 + (idx & 3) * 8], &lB[(size_t)wb * 8]);
        }
        __syncthreads();
        short8_t af[4], bfr[4];
#pragma unroll
        for (int i = 0; i < 4; ++i) af[i] = *(short8_t*)&lA[(wm * 64 + i * 16 + lr) * 32 + lk];
#pragma unroll
        for (int j = 0; j < 4; ++j) bfr[j] = *(short8_t*)&lB[(wn * 64 + j * 16 + lr) * 32 + lk];
#pragma unroll
        for (int i = 0; i < 4; ++i)
#pragma unroll
            for (int j = 0; j < 4; ++j)
                acc[i][j] = __builtin_amdgcn_mfma_f32_16x16x32_bf16(af[i], bfr[j], acc[i][j], 0, 0, 0);
    }
    float cs[4] = {0.f, 0.f, 0.f, 0.f}, css[4] = {0.f, 0.f, 0.f, 0.f};
#pragma unroll
    for (int i = 0; i < 4; ++i) {
#pragma unroll
        for (int r = 0; r < 4; ++r) {
            int row = m0 + wm * 64 + i * 16 + g * 4 + r;
            int bq = row / 320;
            int n = row - bq * 320;
#pragma unroll
            for (int j = 0; j < 4; ++j) {
                float val = acc[i][j][r];
                cs[j] += val;
                css[j] += val * val;
                int col = n0 + wn * 64 + j * 16 + lr;
                int hh = col / 192;
                int cm = col - hh * 192;
                if (cm < 64)
                    qkB[((size_t)(bq * 8 + hh) * 320 + n) * 64 + cm] = f2bf(val);
                else
                    vT[((size_t)(bq * 8 + hh) * 128 + (cm - 64)) * 320 + n] = f2bf(val);
            }
        }
    }
    __syncthreads();
    float* red_s = (float*)lA;
    float* red_ss = (float*)lB;
#pragma unroll
    for (int j = 0; j < 4; ++j) {
        int c = wn * 64 + j * 16 + lr;
        red_s[(wm * 4 + g) * 128 + c] = cs[j];
        red_ss[(wm * 4 + g) * 128 + c] = css[j];
    }
    __syncthreads();
    if (tid < 128) {
        float s = 0.f;
#pragma unroll
        for (int u = 0; u < 8; ++u) s += red_s[u * 128 + tid];
        atomicAdd(&sum1[n0 + tid], s);
    } else {
        int c = tid - 128;
        float s = 0.f;
#pragma unroll
        for (int u = 0; u < 8; ++u) s += red_ss[u * 128 + c];
        atomicAdd(&sumsq1[n0 + c], s);
    }
}

// ---- GEMM2: d_out = attnout @ Wproj^T (f32) via global_load_lds + fused stats ----
__global__ __launch_bounds__(256) void gemm_proj(const unsigned short* __restrict__ A,
                                                 const unsigned short* __restrict__ Bm,
                                                 float* __restrict__ Cout,
                                                 float* __restrict__ sum2, float* __restrict__ sumsq2) {
    __shared__ unsigned short lA[128 * 32];
    __shared__ unsigned short lB[128 * 32];
    const int tid = threadIdx.x;
    const int lane = tid & 63, wid = tid >> 6;
    const int wm = wid >> 1, wn = wid & 1;
    const int lr = lane & 15, g = lane >> 4, lk = g * 8;
    const int m0 = blockIdx.y * 128, n0 = blockIdx.x * 128;
    const int wb0 = tid & 192;
    f32x4 acc[4][4] = {};
    for (int k0 = 0; k0 < 1024; k0 += 32) {
        __syncthreads();
#pragma unroll
        for (int j = 0; j < 2; ++j) {
            int idx = j * 256 + tid;
            int wb = j * 256 + wb0;
            GLD16(&A[(size_t)(m0 + (idx >> 2)) * 1024 + k0 + (idx & 3) * 8], &lA[(size_t)wb * 8]);
            GLD16(&Bm[(size_t)(n0 + (idx >> 2)) * 1024 + k0 + (idx & 3) * 8], &lB[(size_t)wb * 8]);
        }
        __syncthreads();
        short8_t af[4], bfr[4];
#pragma unroll
        for (int i = 0; i < 4; ++i) af[i] = *(short8_t*)&lA[(wm * 64 + i * 16 + lr) * 32 + lk];
#pragma unroll
        for (int j = 0; j < 4; ++j) bfr[j] = *(short8_t*)&lB[(wn * 64 + j * 16 + lr) * 32 + lk];
#pragma unroll
        for (int i = 0; i < 4; ++i)
#pragma unroll
            for (int j = 0; j < 4; ++j)
                acc[i][j] = __builtin_amdgcn_mfma_f32_16x16x32_bf16(af[i], bfr[j], acc[i][j], 0, 0, 0);
    }
    float cs[4] = {0.f, 0.f, 0.f, 0.f}, css[4] = {0.f, 0.f, 0.f, 0.f};
#pragma unroll
    for (int i = 0; i < 4; ++i) {
#pragma unroll
        for (int r = 0; r < 4; ++r) {
            int row = m0 + wm * 64 + i * 16 + g * 4 + r;
#pragma unroll
            for (int j = 0; j < 4; ++j) {
                float val = acc[i][j][r];
                cs[j] += val;
                css[j] += val * val;
                int col = n0 + wn * 64 + j * 16 + lr;
                Cout[(size_t)row * 256 + col] = val;
            }
        }
    }
    __syncthreads();
    float* red_s = (float*)lA;
    float* red_ss = (float*)lB;
#pragma unroll
    for (int j = 0; j < 4; ++j) {
        int c = wn * 64 + j * 16 + lr;
        red_s[(wm * 4 + g) * 128 + c] = cs[j];
        red_ss[(wm * 4 + g) * 128 + c] = css[j];
    }
    __syncthreads();
    if (tid < 128) {
        float s = 0.f;
#pragma unroll
        for (int u = 0; u < 8; ++u) s += red_s[u * 128 + tid];
        atomicAdd(&sum2[n0 + tid], s);
    } else {
        int c = tid - 128;
        float s = 0.f;
#pragma unroll
        for (int u = 0; u < 8; ++u) s += red_ss[u * 128 + c];
        atomicAdd(&sumsq2[n0 + c], s);
    }
}

__global__ void bn_finalize(const float* __restrict__ sum, const float* __restrict__ sumsq,
                            const float* __restrict__ g, const float* __restrict__ b,
                            float* __restrict__ scale, float* __restrict__ shift, int C, float invM) {
    int c = blockIdx.x * 256 + threadIdx.x;
    if (c < C) {
        float mean = sum[c] * invM;
        float var = sumsq[c] * invM - mean * mean;
        float sc = g[c] * rsqrtf(var + EPS);
        scale[c] = sc;
        shift[c] = b[c] - mean * sc;
    }
}

__global__ void prep_w(const float* __restrict__ scale1, const float* __restrict__ shift1,
                       float* __restrict__ wq, float* __restrict__ w2) {
    int c = threadIdx.x;
    if (c < 256) {
        int h = c >> 5, cc = c & 31;
        int qch = h * 192 + cc, kch = qch + 32;
        wq[c] = scale1[qch] * scale1[kch] * SCALE;
        w2[c] = shift1[qch] * scale1[kch] * SCALE;
    }
}

__global__ void uk_kernel(const unsigned short* __restrict__ qkB, const float* __restrict__ w2,
                          float* __restrict__ uk) {
    int idx = blockIdx.x * 256 + threadIdx.x;
    if (idx < 128 * 8 * 320) {
        int bh = idx / 320;
        int h = bh & 7;
        const unsigned short* kp = &qkB[(size_t)idx * 64 + 32];
        float s = 0.f;
#pragma unroll
        for (int c4 = 0; c4 < 4; ++c4) {
            short8_t kk = *(const short8_t*)&kp[c4 * 8];
#pragma unroll
            for (int j = 0; j < 8; ++j) s += bf2f((unsigned short)kk[j]) * w2[(h << 5) + c4 * 8 + j];
        }
        uk[idx] = s;
    }
}

__global__ void bias_build(const float* __restrict__ ab, const int* __restrict__ idxs,
                           unsigned short* __restrict__ biasb, int n_off) {
    int i = blockIdx.x * 256 + threadIdx.x;
    if (i < H_ * N_ * N_) {
        int h = i / (N_ * N_);
        int r = i % (N_ * N_);
        biasb[i] = f2bf(ab[h * n_off + idxs[r]]);
    }
}

// ---- attention v5: round-5 structure + swapped QK^T (S stored m-major per lane) ----
// block=(h, b*5+qt), 4 waves. Swapped mfma(K,Q): lane holds S[m0..m0+3][n=lr] ->
// bias/uk vector loads, b64 P-store, 2-shuffle rowsum. PV: wave owns 32 O-cols, reads all P slabs.
__global__ __launch_bounds__(256) void attn_kernel(const unsigned short* __restrict__ qkB,
                                                   const unsigned short* __restrict__ vT,
                                                   const float* __restrict__ wq,
                                                   const float* __restrict__ uk,
                                                   const unsigned short* __restrict__ biasb,
                                                   const float* __restrict__ scale1,
                                                   const float* __restrict__ shift1,
                                                   unsigned short* __restrict__ attnout) {
    __shared__ unsigned short Plds[4][16][328];  // [q-wave][n][m+pad], XOR-swizzled in m
    __shared__ float sums[64];
    const int tid = threadIdx.x;
    const int lane = tid & 63, wid = tid >> 6;
    const int lr = lane & 15, g = lane >> 4;
    const int h = blockIdx.x;
    const int b = blockIdx.y / 5, qt = blockIdx.y % 5;
    const int bh = b * 8 + h;

    // Q fragment (wq = sq*sk*SCALE folded in)
    const int qrow = qt * 64 + wid * 16 + lr;  // this lane's q-row (n), fixed all phases
    short8_t qraw = *(const short8_t*)&qkB[((size_t)bh * 320 + qrow) * 64 + g * 8];
    f32x4 wq0 = *(const f32x4*)&wq[(h << 5) + g * 8];
    f32x4 wq1 = *(const f32x4*)&wq[(h << 5) + g * 8 + 4];
    short8_t aq;
#pragma unroll
    for (int j = 0; j < 4; ++j) {
        aq[j] = (short)f2bf(bf2f((unsigned short)qraw[j]) * wq0[j]);
        aq[4 + j] = (short)f2bf(bf2f((unsigned short)qraw[4 + j]) * wq1[j]);
    }

    // phase 1: QK^T swapped -> sacc[t] rows are m, col = n = lr
    const unsigned short* Kbase = &qkB[(size_t)bh * 320 * 64 + 32 + g * 8];
    f32x4 sacc[20];
#pragma unroll
    for (int t = 0; t < 20; ++t) {
        short8_t bk = *(const short8_t*)&Kbase[(size_t)(t * 16 + lr) * 64];
        f32x4 z = {};
        sacc[t] = __builtin_amdgcn_mfma_f32_16x16x32_bf16(bk, aq, z, 0, 0, 0);
    }

    // phase 2: bias + uk + exp -> P slab (vectorized), rowsum
    const unsigned short* brow = &biasb[(size_t)h * 102400 + (size_t)qrow * 320];
    const float* ukrow = &uk[(size_t)bh * 320];
    const int swz = (lr & 3) << 3;
    float sumr = 0.f;
#pragma unroll
    for (int t = 0; t < 20; ++t) {
        int m0 = t * 16 + g * 4;
        short4_t b4 = *(const short4_t*)&brow[m0];
        f32x4 uk4 = *(const f32x4*)&ukrow[m0];
        float p0 = __expf(sacc[t][0] + uk4[0] + bf2f((unsigned short)b4[0]));
        float p1 = __expf(sacc[t][1] + uk4[1] + bf2f((unsigned short)b4[1]));
        float p2 = __expf(sacc[t][2] + uk4[2] + bf2f((unsigned short)b4[2]));
        float p3 = __expf(sacc[t][3] + uk4[3] + bf2f((unsigned short)b4[3]));
        sumr += (p0 + p1) + (p2 + p3);
        uint2 pk = make_uint2(f2bf2(p0, p1), f2bf2(p2, p3));
        *(uint2*)&Plds[wid][lr][m0 ^ swz] = pk;
    }
    sumr += __shfl_xor(sumr, 16);
    sumr += __shfl_xor(sumr, 32);
    if (lane < 16) sums[wid * 16 + lr] = sumr;
    __syncthreads();

    // phase 3: PV. wave owns O-cols [wid*32, wid*32+32); reads all 4 P slabs
    const unsigned short* Vb = &vT[(size_t)bh * 128 * 320 + g * 8];
    f32x4 oacc[4][2] = {};
#pragma unroll
    for (int t = 0; t < 10; ++t) {
        short8_t bv0 = *(const short8_t*)&Vb[(size_t)(wid * 32 + lr) * 320 + t * 32];
        short8_t bv1 = *(const short8_t*)&Vb[(size_t)(wid * 32 + 16 + lr) * 320 + t * 32];
        int m8 = (t * 32 + g * 8) ^ swz;
#pragma unroll
        for (int qw = 0; qw < 4; ++qw) {
            short8_t ap = *(short8_t*)&Plds[qw][lr][m8];
            oacc[qw][0] = __builtin_amdgcn_mfma_f32_16x16x32_bf16(ap, bv0, oacc[qw][0], 0, 0, 0);
            oacc[qw][1] = __builtin_amdgcn_mfma_f32_16x16x32_bf16(ap, bv1, oacc[qw][1], 0, 0, 0);
        }
    }

    // epilogue: normalize, fold V-BN, GELU
    float svv[2], tvv[2];
#pragma unroll
    for (int dtl = 0; dtl < 2; ++dtl) {
        int ch = h * 192 + 64 + wid * 32 + dtl * 16 + lr;
        svv[dtl] = scale1[ch];
        tvv[dtl] = shift1[ch];
    }
#pragma unroll
    for (int qw = 0; qw < 4; ++qw) {
#pragma unroll
        for (int r = 0; r < 4; ++r) {
            float inv = 1.0f / sums[qw * 16 + g * 4 + r];
            size_t nrow = (size_t)b * 320 + qt * 64 + qw * 16 + g * 4 + r;
#pragma unroll
            for (int dtl = 0; dtl < 2; ++dtl) {
                float v = oacc[qw][dtl][r] * inv * svv[dtl] + tvv[dtl];
                attnout[nrow * 1024 + h * 128 + wid * 32 + dtl * 16 + lr] = f2bf(gelu_f(v));
            }
        }
    }
}

__global__ void bn_apply(float* __restrict__ out, const float* __restrict__ scale,
                         const float* __restrict__ shift) {
    int i = blockIdx.x * 256 + threadIdx.x;
    const int total = MROWS * C_ / 4;
    for (; i < total; i += gridDim.x * 256) {
        f32x4 v = *(const f32x4*)&out[(size_t)i * 4];
        int c = (i * 4) & 255;
        f32x4 o;
#pragma unroll
        for (int j = 0; j < 4; ++j) o[j] = v[j] * scale[c + j] + shift[c + j];
        *(f32x4*)&out[(size_t)i * 4] = o;
    }
}

extern "C" void kernel_launch(void* const* d_in, const int* in_sizes, int n_in,
                              void* d_out, int out_size, void* d_ws, size_t ws_size,
                              hipStream_t stream) {
    const float* x = (const float*)d_in[0];
    const float* Wqkv = (const float*)d_in[1];
    const float* g1 = (const float*)d_in[2];
    const float* b1 = (const float*)d_in[3];
    const float* ab = (const float*)d_in[4];
    const float* Wproj = (const float*)d_in[5];
    const float* g2 = (const float*)d_in[6];
    const float* b2 = (const float*)d_in[7];
    const int* idxs = (const int*)d_in[8];
    const int n_off = in_sizes[4] / H_;

    char* ws = (char*)d_ws;
    unsigned short* qkB = (unsigned short*)ws;                       // 41.9MB
    unsigned short* vT = (unsigned short*)(ws + 41943040);           // 83.9MB
    unsigned short* attnout = (unsigned short*)(ws + 125829120);     // 83.9MB
    unsigned short* xb = attnout;                                    // overlap: dead before attn
    unsigned short* biasb = (unsigned short*)(ws + 209715200);       // 1.64MB bf16
    float* uk = (float*)(ws + 212992000);                            // 1.31MB
    unsigned short* wqb = (unsigned short*)(ws + 214302720);
    unsigned short* wpb = (unsigned short*)(ws + 215089152);
    float* stats = (float*)(ws + 215613440);
    float* sum1 = stats;
    float* sumsq1 = stats + 1536;
    float* sum2 = stats + 3072;
    float* sumsq2 = sum2 + 256;
    float* scale1 = sumsq2 + 256;
    float* shift1 = scale1 + 1536;
    float* scale2 = shift1 + 1536;
    float* shift2 = scale2 + 256;
    float* wq = shift2 + 256;
    float* w2 = wq + 256;

    hipMemsetAsync(stats, 0, 3584 * 4, stream);
    conv_all<<<dim3(10880), 256, 0, stream>>>(x, Wqkv, Wproj, xb, wqb, wpb);
    bias_build<<<dim3(3200), 256, 0, stream>>>(ab, idxs, biasb, n_off);
    gemm_qkv<<<dim3(12, 320), 256, 0, stream>>>(xb, wqb, qkB, vT, sum1, sumsq1);
    bn_finalize<<<dim3(6), 256, 0, stream>>>(sum1, sumsq1, g1, b1, scale1, shift1, 1536, 1.0f / MROWS);
    prep_w<<<dim3(1), 256, 0, stream>>>(scale1, shift1, wq, w2);
    uk_kernel<<<dim3(1280), 256, 0, stream>>>(qkB, w2, uk);
    attn_kernel<<<dim3(8, 640), 256, 0, stream>>>(qkB, vT, wq, uk, biasb, scale1, shift1, attnout);
    gemm_proj<<<dim3(2, 320), 256, 0, stream>>>(attnout, wpb, (float*)d_out, sum2, sumsq2);
    bn_finalize<<<dim3(1), 256, 0, stream>>>(sum2, sumsq2, g2, b2, scale2, shift2, 256, 1.0f / MROWS);
    bn_apply<<<dim3(2048), 256, 0, stream>>>((float*)d_out, scale2, shift2);
}

// Round 8
// 301.684 us; speedup vs baseline: 1.3901x; 1.3329x over previous
//
#include <hip/hip_runtime.h>
#include <hip/hip_bf16.h>

#define B_ 128
#define N_ 320
#define C_ 256
#define H_ 8
#define HQKV 1536
#define DH 1024
#define MROWS 40960
#define EPS 1e-5f
#define SCALE 0.17677669529663687f
#define LOG2E 1.4426950408889634f

typedef __attribute__((ext_vector_type(4))) float f32x4;
typedef __attribute__((ext_vector_type(8))) short short8_t;
typedef __attribute__((ext_vector_type(4))) short short4_t;

__device__ inline float bf2f(unsigned short u) { return __uint_as_float(((unsigned)u) << 16); }
__device__ inline unsigned short f2bf(float f) {
    unsigned u = __float_as_uint(f);
    u += 0x7FFF + ((u >> 16) & 1);
    return (unsigned short)(u >> 16);
}

// sigmoid-form tanh-GELU: v*sigmoid(1.5957691*(v+0.044715 v^3)); exp2/rcp HW ops (8 VALU)
__device__ inline float gelu_f(float v) {
    float v2 = v * v;
    float w = fmaf(v2, 0.044715f, 1.0f);
    float z = v * w * (-2.3022098f);  // -1.5957691216 * log2(e)
    float e = __builtin_amdgcn_exp2f(z);
    return v * __builtin_amdgcn_rcpf(1.0f + e);
}

#define GLD16(gp, lp)                                                                  \
    __builtin_amdgcn_global_load_lds((const __attribute__((address_space(1))) void*)(gp), \
                                     (__attribute__((address_space(3))) void*)(lp), 16, 0, 0)

__global__ void conv_all(const float* __restrict__ x, const float* __restrict__ wqkv,
                         const float* __restrict__ wproj, unsigned short* __restrict__ xb,
                         unsigned short* __restrict__ wqb, unsigned short* __restrict__ wpb) {
    int i = blockIdx.x * 256 + threadIdx.x;
    const float* src;
    unsigned short* dst;
    int off;
    if (i < 2621440) { src = x; dst = xb; off = i; }
    else if (i < 2719744) { src = wqkv; dst = wqb; off = i - 2621440; }
    else if (i < 2785280) { src = wproj; dst = wpb; off = i - 2719744; }
    else return;
    f32x4 v = ((const f32x4*)src)[off];
    short4_t o;
#pragma unroll
    for (int j = 0; j < 4; ++j) o[j] = (short)f2bf(v[j]);
    ((short4_t*)dst)[off] = o;
}

// ---- GEMM1: qkv = x @ Wqkv^T via global_load_lds; routes q/k/v; fused BN stats ----
__global__ __launch_bounds__(256) void gemm_qkv(const unsigned short* __restrict__ A,
                                                const unsigned short* __restrict__ Bm,
                                                unsigned short* __restrict__ qkB,
                                                unsigned short* __restrict__ vT,
                                                float* __restrict__ sum1, float* __restrict__ sumsq1) {
    __shared__ unsigned short lA[128 * 32];
    __shared__ unsigned short lB[128 * 32];
    const int tid = threadIdx.x;
    const int lane = tid & 63, wid = tid >> 6;
    const int wm = wid >> 1, wn = wid & 1;
    const int lr = lane & 15, g = lane >> 4, lk = g * 8;
    const int m0 = blockIdx.y * 128, n0 = blockIdx.x * 128;
    const int wb0 = tid & 192;
    f32x4 acc[4][4] = {};
    for (int k0 = 0; k0 < 256; k0 += 32) {
        __syncthreads();
#pragma unroll
        for (int j = 0; j < 2; ++j) {
            int idx = j * 256 + tid;
            int wb = j * 256 + wb0;
            GLD16(&A[(size_t)(m0 + (idx >> 2)) * 256 + k0 + (idx & 3) * 8], &lA[(size_t)wb * 8]);
            GLD16(&Bm[(size_t)(n0 + (idx >> 2)) * 256 + k0 + (idx & 3) * 8], &lB[(size_t)wb * 8]);
        }
        __syncthreads();
        short8_t af[4], bfr[4];
#pragma unroll
        for (int i = 0; i < 4; ++i) af[i] = *(short8_t*)&lA[(wm * 64 + i * 16 + lr) * 32 + lk];
#pragma unroll
        for (int j = 0; j < 4; ++j) bfr[j] = *(short8_t*)&lB[(wn * 64 + j * 16 + lr) * 32 + lk];
#pragma unroll
        for (int i = 0; i < 4; ++i)
#pragma unroll
            for (int j = 0; j < 4; ++j)
                acc[i][j] = __builtin_amdgcn_mfma_f32_16x16x32_bf16(af[i], bfr[j], acc[i][j], 0, 0, 0);
    }
    // epilogue: hoisted routing, vectorized vT stores, per-column stats
    int hhj[4], cmj[4];
#pragma unroll
    for (int j = 0; j < 4; ++j) {
        int col = n0 + wn * 64 + j * 16 + lr;
        hhj[j] = col / 192;
        cmj[j] = col - hhj[j] * 192;
    }
    float cs[4] = {0.f, 0.f, 0.f, 0.f}, css[4] = {0.f, 0.f, 0.f, 0.f};
#pragma unroll
    for (int i = 0; i < 4; ++i) {
        int rowbase = m0 + wm * 64 + i * 16 + g * 4;  // 4-aligned: never crosses a 320 boundary
        int bq = rowbase / 320;
        int n = rowbase - bq * 320;
#pragma unroll
        for (int j = 0; j < 4; ++j) {
            float v0 = acc[i][j][0], v1 = acc[i][j][1], v2 = acc[i][j][2], v3 = acc[i][j][3];
            cs[j] += (v0 + v1) + (v2 + v3);
            css[j] += (v0 * v0 + v1 * v1) + (v2 * v2 + v3 * v3);
            if (cmj[j] < 64) {
                unsigned short* qp = &qkB[((size_t)(bq * 8 + hhj[j]) * 320 + n) * 64 + cmj[j]];
                qp[0] = f2bf(v0); qp[64] = f2bf(v1); qp[128] = f2bf(v2); qp[192] = f2bf(v3);
            } else {
                short4_t o;
                o[0] = (short)f2bf(v0); o[1] = (short)f2bf(v1);
                o[2] = (short)f2bf(v2); o[3] = (short)f2bf(v3);
                *(short4_t*)&vT[((size_t)(bq * 8 + hhj[j]) * 128 + (cmj[j] - 64)) * 320 + n] = o;
            }
        }
    }
    __syncthreads();
    float* red_s = (float*)lA;
    float* red_ss = (float*)lB;
#pragma unroll
    for (int j = 0; j < 4; ++j) {
        int c = wn * 64 + j * 16 + lr;
        red_s[(wm * 4 + g) * 128 + c] = cs[j];
        red_ss[(wm * 4 + g) * 128 + c] = css[j];
    }
    __syncthreads();
    if (tid < 128) {
        float s = 0.f;
#pragma unroll
        for (int u = 0; u < 8; ++u) s += red_s[u * 128 + tid];
        atomicAdd(&sum1[n0 + tid], s);
    } else {
        int c = tid - 128;
        float s = 0.f;
#pragma unroll
        for (int u = 0; u < 8; ++u) s += red_ss[u * 128 + c];
        atomicAdd(&sumsq1[n0 + c], s);
    }
}

// ---- GEMM2: 64x128 tile (better occupancy: 1280 blocks), fused stats ----
__global__ __launch_bounds__(256) void gemm_proj(const unsigned short* __restrict__ A,
                                                 const unsigned short* __restrict__ Bm,
                                                 float* __restrict__ Cout,
                                                 float* __restrict__ sum2, float* __restrict__ sumsq2) {
    __shared__ unsigned short lA[64 * 32];
    __shared__ unsigned short lB[128 * 32];
    const int tid = threadIdx.x;
    const int lane = tid & 63, wid = tid >> 6;
    const int wm = wid >> 1, wn = wid & 1;
    const int lr = lane & 15, g = lane >> 4, lk = g * 8;
    const int m0 = blockIdx.y * 64, n0 = blockIdx.x * 128;
    const int wb0 = tid & 192;
    f32x4 acc[2][4] = {};
    for (int k0 = 0; k0 < 1024; k0 += 32) {
        __syncthreads();
        GLD16(&A[(size_t)(m0 + (tid >> 2)) * 1024 + k0 + (tid & 3) * 8], &lA[(size_t)wb0 * 8]);
        GLD16(&Bm[(size_t)(n0 + (tid >> 2)) * 1024 + k0 + (tid & 3) * 8], &lB[(size_t)wb0 * 8]);
        GLD16(&Bm[(size_t)(n0 + 64 + (tid >> 2)) * 1024 + k0 + (tid & 3) * 8], &lB[2048 + (size_t)wb0 * 8]);
        __syncthreads();
        short8_t af[2], bfr[4];
#pragma unroll
        for (int i = 0; i < 2; ++i) af[i] = *(short8_t*)&lA[(wm * 32 + i * 16 + lr) * 32 + lk];
#pragma unroll
        for (int j = 0; j < 4; ++j) bfr[j] = *(short8_t*)&lB[(wn * 64 + j * 16 + lr) * 32 + lk];
#pragma unroll
        for (int i = 0; i < 2; ++i)
#pragma unroll
            for (int j = 0; j < 4; ++j)
                acc[i][j] = __builtin_amdgcn_mfma_f32_16x16x32_bf16(af[i], bfr[j], acc[i][j], 0, 0, 0);
    }
    float cs[4] = {0.f, 0.f, 0.f, 0.f}, css[4] = {0.f, 0.f, 0.f, 0.f};
#pragma unroll
    for (int i = 0; i < 2; ++i) {
#pragma unroll
        for (int r = 0; r < 4; ++r) {
            int row = m0 + wm * 32 + i * 16 + g * 4 + r;
#pragma unroll
            for (int j = 0; j < 4; ++j) {
                float val = acc[i][j][r];
                cs[j] += val;
                css[j] += val * val;
                Cout[(size_t)row * 256 + n0 + wn * 64 + j * 16 + lr] = val;
            }
        }
    }
    __syncthreads();
    float* red_s = (float*)lB;               // 4KB needed, lB is 8KB
    float* red_ss = (float*)lB + 1024;
#pragma unroll
    for (int j = 0; j < 4; ++j) {
        int c = wn * 64 + j * 16 + lr;
        red_s[(wm * 4 + g) * 128 + c] = cs[j];
        red_ss[(wm * 4 + g) * 128 + c] = css[j];
    }
    __syncthreads();
    if (tid < 128) {
        float s = 0.f;
#pragma unroll
        for (int u = 0; u < 8; ++u) s += red_s[u * 128 + tid];
        atomicAdd(&sum2[n0 + tid], s);
    } else {
        int c = tid - 128;
        float s = 0.f;
#pragma unroll
        for (int u = 0; u < 8; ++u) s += red_ss[u * 128 + c];
        atomicAdd(&sumsq2[n0 + c], s);
    }
}

__global__ void bn_finalize(const float* __restrict__ sum, const float* __restrict__ sumsq,
                            const float* __restrict__ g, const float* __restrict__ b,
                            float* __restrict__ scale, float* __restrict__ shift, int C, float invM) {
    int c = blockIdx.x * 256 + threadIdx.x;
    if (c < C) {
        float mean = sum[c] * invM;
        float var = sumsq[c] * invM - mean * mean;
        float sc = g[c] * rsqrtf(var + EPS);
        scale[c] = sc;
        shift[c] = b[c] - mean * sc;
    }
}

// wq/w2 carry SCALE*log2(e) so softmax is a bare v_exp_f32 (exp2)
__global__ void prep_w(const float* __restrict__ scale1, const float* __restrict__ shift1,
                       float* __restrict__ wq, float* __restrict__ w2) {
    int c = threadIdx.x;
    if (c < 256) {
        int h = c >> 5, cc = c & 31;
        int qch = h * 192 + cc, kch = qch + 32;
        wq[c] = scale1[qch] * scale1[kch] * (SCALE * LOG2E);
        w2[c] = shift1[qch] * scale1[kch] * (SCALE * LOG2E);
    }
}

__global__ void uk_kernel(const unsigned short* __restrict__ qkB, const float* __restrict__ w2,
                          float* __restrict__ uk) {
    int idx = blockIdx.x * 256 + threadIdx.x;
    if (idx < 128 * 8 * 320) {
        int bh = idx / 320;
        int h = bh & 7;
        const unsigned short* kp = &qkB[(size_t)idx * 64 + 32];
        float s = 0.f;
#pragma unroll
        for (int c4 = 0; c4 < 4; ++c4) {
            short8_t kk = *(const short8_t*)&kp[c4 * 8];
#pragma unroll
            for (int j = 0; j < 8; ++j) s += bf2f((unsigned short)kk[j]) * w2[(h << 5) + c4 * 8 + j];
        }
        uk[idx] = s;
    }
}

__global__ void bias_build(const float* __restrict__ ab, const int* __restrict__ idxs,
                           unsigned short* __restrict__ biasb, int n_off) {
    int i = blockIdx.x * 256 + threadIdx.x;
    if (i < H_ * N_ * N_) {
        int h = i / (N_ * N_);
        int r = i % (N_ * N_);
        biasb[i] = f2bf(ab[h * n_off + idxs[r]] * LOG2E);
    }
}

// ---- attention (R5 structure): block=(h, b*5+qt), 4 waves, phase-split, V read once/block ----
__global__ __launch_bounds__(256) void attn_kernel(const unsigned short* __restrict__ qkB,
                                                   const unsigned short* __restrict__ vT,
                                                   const float* __restrict__ wq,
                                                   const float* __restrict__ uk,
                                                   const unsigned short* __restrict__ biasb,
                                                   const float* __restrict__ scale1,
                                                   const float* __restrict__ shift1,
                                                   unsigned short* __restrict__ attnout) {
    __shared__ unsigned short Plds[4][10][16][40];
    __shared__ float sums[64];
    const int tid = threadIdx.x;
    const int lane = tid & 63, wid = tid >> 6;
    const int lr = lane & 15, g = lane >> 4;
    const int h = blockIdx.x;
    const int b = blockIdx.y / 5, qt = blockIdx.y % 5;
    const int bh = b * 8 + h;

    int qrow = qt * 64 + wid * 16 + lr;
    short8_t qraw = *(const short8_t*)&qkB[((size_t)bh * 320 + qrow) * 64 + g * 8];
    short8_t aq;
#pragma unroll
    for (int j = 0; j < 8; ++j)
        aq[j] = (short)f2bf(bf2f((unsigned short)qraw[j]) * wq[(h << 5) + g * 8 + j]);

    // phase 1: QK^T (independent L2 K-loads)
    const unsigned short* Kbase = &qkB[(size_t)bh * 320 * 64 + 32 + g * 8];
    f32x4 sacc[20];
#pragma unroll
    for (int t = 0; t < 20; ++t) {
        short8_t bk = *(const short8_t*)&Kbase[(size_t)(t * 16 + lr) * 64];
        f32x4 z = {};
        sacc[t] = __builtin_amdgcn_mfma_f32_16x16x32_bf16(aq, bk, z, 0, 0, 0);
    }

    // phase 2: bias + uk + exp2 -> P slab, rowsum
    const int nloc0 = qt * 64 + wid * 16 + g * 4;
    const unsigned short* biasrow = &biasb[(size_t)h * 102400];
    const float* ukrow = &uk[(size_t)bh * 320];
    float sumr[4] = {0.f, 0.f, 0.f, 0.f};
#pragma unroll
    for (int t = 0; t < 20; ++t) {
        float ukv = ukrow[t * 16 + lr];
#pragma unroll
        for (int r = 0; r < 4; ++r) {
            float s = sacc[t][r] + ukv + bf2f(biasrow[(size_t)(nloc0 + r) * 320 + t * 16 + lr]);
            float p = __builtin_amdgcn_exp2f(s);
            sumr[r] += p;
            Plds[wid][t >> 1][g * 4 + r][(t & 1) * 16 + lr] = f2bf(p);
        }
    }
#pragma unroll
    for (int r = 0; r < 4; ++r) {
#pragma unroll
        for (int ms = 1; ms < 16; ms <<= 1) sumr[r] += __shfl_xor(sumr[r], ms);
        if (lr == 0) sums[wid * 16 + g * 4 + r] = sumr[r];
    }
    __syncthreads();

    // phase 3: PV. wave owns O-cols [wid*32, wid*32+32); reads all 4 P slabs
    const unsigned short* Vb = &vT[(size_t)bh * 128 * 320 + g * 8];
    f32x4 oacc[4][2] = {};
#pragma unroll
    for (int t = 0; t < 10; ++t) {
        short8_t bv0 = *(const short8_t*)&Vb[(size_t)(wid * 32 + lr) * 320 + t * 32];
        short8_t bv1 = *(const short8_t*)&Vb[(size_t)(wid * 32 + 16 + lr) * 320 + t * 32];
#pragma unroll
        for (int qw = 0; qw < 4; ++qw) {
            short8_t ap = *(short8_t*)&Plds[qw][t][lr][g * 8];
            oacc[qw][0] = __builtin_amdgcn_mfma_f32_16x16x32_bf16(ap, bv0, oacc[qw][0], 0, 0, 0);
            oacc[qw][1] = __builtin_amdgcn_mfma_f32_16x16x32_bf16(ap, bv1, oacc[qw][1], 0, 0, 0);
        }
    }

    // epilogue: normalize, fold V-BN, GELU
    float svv[2], tvv[2];
#pragma unroll
    for (int dtl = 0; dtl < 2; ++dtl) {
        int ch = h * 192 + 64 + wid * 32 + dtl * 16 + lr;
        svv[dtl] = scale1[ch];
        tvv[dtl] = shift1[ch];
    }
#pragma unroll
    for (int qw = 0; qw < 4; ++qw) {
#pragma unroll
        for (int r = 0; r < 4; ++r) {
            float inv = __builtin_amdgcn_rcpf(sums[qw * 16 + g * 4 + r]);
            size_t nrow = (size_t)b * 320 + qt * 64 + qw * 16 + g * 4 + r;
#pragma unroll
            for (int dtl = 0; dtl < 2; ++dtl) {
                float v = oacc[qw][dtl][r] * inv * svv[dtl] + tvv[dtl];
                attnout[nrow * 1024 + h * 128 + wid * 32 + dtl * 16 + lr] = f2bf(gelu_f(v));
            }
        }
    }
}

__global__ void bn_apply(float* __restrict__ out, const float* __restrict__ scale,
                         const float* __restrict__ shift) {
    int i = blockIdx.x * 256 + threadIdx.x;
    const int total = MROWS * C_ / 4;
    for (; i < total; i += gridDim.x * 256) {
        f32x4 v = *(const f32x4*)&out[(size_t)i * 4];
        int c = (i * 4) & 255;
        f32x4 o;
#pragma unroll
        for (int j = 0; j < 4; ++j) o[j] = v[j] * scale[c + j] + shift[c + j];
        *(f32x4*)&out[(size_t)i * 4] = o;
    }
}

extern "C" void kernel_launch(void* const* d_in, const int* in_sizes, int n_in,
                              void* d_out, int out_size, void* d_ws, size_t ws_size,
                              hipStream_t stream) {
    const float* x = (const float*)d_in[0];
    const float* Wqkv = (const float*)d_in[1];
    const float* g1 = (const float*)d_in[2];
    const float* b1 = (const float*)d_in[3];
    const float* ab = (const float*)d_in[4];
    const float* Wproj = (const float*)d_in[5];
    const float* g2 = (const float*)d_in[6];
    const float* b2 = (const float*)d_in[7];
    const int* idxs = (const int*)d_in[8];
    const int n_off = in_sizes[4] / H_;

    char* ws = (char*)d_ws;
    unsigned short* qkB = (unsigned short*)ws;                       // 41.9MB
    unsigned short* vT = (unsigned short*)(ws + 41943040);           // 83.9MB
    unsigned short* attnout = (unsigned short*)(ws + 125829120);     // 83.9MB
    unsigned short* xb = attnout;                                    // overlap: dead before attn
    unsigned short* biasb = (unsigned short*)(ws + 209715200);       // bf16, pre-scaled by log2e
    float* uk = (float*)(ws + 212992000);
    unsigned short* wqb = (unsigned short*)(ws + 214302720);
    unsigned short* wpb = (unsigned short*)(ws + 215089152);
    float* stats = (float*)(ws + 215613440);
    float* sum1 = stats;
    float* sumsq1 = stats + 1536;
    float* sum2 = stats + 3072;
    float* sumsq2 = sum2 + 256;
    float* scale1 = sumsq2 + 256;
    float* shift1 = scale1 + 1536;
    float* scale2 = shift1 + 1536;
    float* shift2 = scale2 + 256;
    float* wq = shift2 + 256;
    float* w2 = wq + 256;

    hipMemsetAsync(stats, 0, 3584 * 4, stream);
    conv_all<<<dim3(10880), 256, 0, stream>>>(x, Wqkv, Wproj, xb, wqb, wpb);
    bias_build<<<dim3(3200), 256, 0, stream>>>(ab, idxs, biasb, n_off);
    gemm_qkv<<<dim3(12, 320), 256, 0, stream>>>(xb, wqb, qkB, vT, sum1, sumsq1);
    bn_finalize<<<dim3(6), 256, 0, stream>>>(sum1, sumsq1, g1, b1, scale1, shift1, 1536, 1.0f / MROWS);
    prep_w<<<dim3(1), 256, 0, stream>>>(scale1, shift1, wq, w2);
    uk_kernel<<<dim3(1280), 256, 0, stream>>>(qkB, w2, uk);
    attn_kernel<<<dim3(8, 640), 256, 0, stream>>>(qkB, vT, wq, uk, biasb, scale1, shift1, attnout);
    gemm_proj<<<dim3(2, 640), 256, 0, stream>>>(attnout, wpb, (float*)d_out, sum2, sumsq2);
    bn_finalize<<<dim3(1), 256, 0, stream>>>(sum2, sumsq2, g2, b2, scale2, shift2, 256, 1.0f / MROWS);
    bn_apply<<<dim3(2048), 256, 0, stream>>>((float*)d_out, scale2, shift2);
}